// Round 10
// baseline (2085.668 us; speedup 1.0000x reference)
//
#include <hip/hip_runtime.h>
#include <math.h>

#define D_MODEL 1024
#define N_HEADS 16
#define HEAD_DIM 64
#define D_FF 4096
#define N_LAYERS 4
#define VOCAB 2048
#define NUM_GROUPS 15
#define CACHE_LEN 17
#define EPS 1e-6f
#define NB 256   // blocks (1 per CU)
#define NT 1024  // threads per block (16 waves)

typedef unsigned short ushort8v __attribute__((ext_vector_type(8)));

// ---------- coherent (device-scope) accessors ----------
__device__ __forceinline__ float ldc(const float* p) {
  return __hip_atomic_load((float*)p, __ATOMIC_RELAXED, __HIP_MEMORY_SCOPE_AGENT);
}
__device__ __forceinline__ void stc(float* p, float v) {
  __hip_atomic_store(p, v, __ATOMIC_RELAXED, __HIP_MEMORY_SCOPE_AGENT);
}
__device__ __forceinline__ void stc2(float* p, float a, float b) {
  union { unsigned long long u; float2 f; } c;
  c.f = make_float2(a, b);
  __hip_atomic_store((unsigned long long*)p, c.u, __ATOMIC_RELAXED,
                     __HIP_MEMORY_SCOPE_AGENT);
}
__device__ __forceinline__ void stc_u64(unsigned long long* p, unsigned long long v) {
  __hip_atomic_store(p, v, __ATOMIC_RELAXED, __HIP_MEMORY_SCOPE_AGENT);
}
__device__ __forceinline__ unsigned ldu(const unsigned* p) {
  return __hip_atomic_load((unsigned*)p, __ATOMIC_RELAXED, __HIP_MEMORY_SCOPE_AGENT);
}

__device__ __forceinline__ float bf2f(unsigned short u) {
  union { unsigned int i; float f; } c;
  c.i = ((unsigned int)u) << 16;
  return c.f;
}
__device__ __forceinline__ unsigned short f2bf(float f) {
  union { float f; unsigned int i; } c;
  c.f = f;
  unsigned int r = (c.i + 0x7fffu + ((c.i >> 16) & 1u)) >> 16;
  return (unsigned short)r;
}

__device__ __forceinline__ float wred(float v) {
#pragma unroll
  for (int o = 32; o > 0; o >>= 1) v += __shfl_xor(v, o, 64);
  return v;
}
__device__ __forceinline__ float wredmax(float v) {
#pragma unroll
  for (int o = 32; o > 0; o >>= 1) v = fmaxf(v, __shfl_xor(v, o, 64));
  return v;
}

// ---------- split flag-array grid barrier ----------
// flags[b*16] (64B apart), zeroed per call. begin = arrive; end = poll.
// Poll: thread t (t<NB) spins on block t's flag only; __syncthreads joins.
// Weight prefetch loads are issued BETWEEN begin and end to hide latency.
__device__ __forceinline__ void gsync_begin(unsigned* flags, unsigned gen) {
  __syncthreads();
  if (threadIdx.x == 0)
    __hip_atomic_store(flags + (size_t)blockIdx.x * 16u, gen, __ATOMIC_RELAXED,
                       __HIP_MEMORY_SCOPE_AGENT);
}
__device__ __forceinline__ void gsync_end(unsigned* flags, unsigned gen) {
  if (threadIdx.x < NB) {
    const unsigned* f = flags + (size_t)threadIdx.x * 16u;
    while (ldu(f) < gen) __builtin_amdgcn_s_sleep(1);
  }
  __syncthreads();
}

// ---------- transposed-subtile weight access ----------
// bf16 storage: 16B word [(row*nsub + it)*64 + lane] holds elements
// {row*IN + it*512 + c*64 + lane}, c=0..7 (IN = nsub*512).
// f32 fallback: linear rows, scalar gather at the same element positions.
template <int BF>
__device__ __forceinline__ void ldsub(const unsigned short* Wb, const float* Wf,
                                      size_t row, int nsub, int it, ushort8v& ob,
                                      float* of) {
  int lane = threadIdx.x & 63;
  if constexpr (BF) {
    ob = ((const ushort8v*)Wb)[(row * nsub + it) * 64 + lane];
  } else {
    const float* p = Wf + row * (size_t)nsub * 512 + it * 512 + lane;
#pragma unroll
    for (int c = 0; c < 8; ++c) of[c] = p[c * 64];
  }
}

template <int BF>
__device__ __forceinline__ float dsub(const ushort8v& wb, const float* wf,
                                      const float* a8) {
  float acc = 0.f;
  if constexpr (BF) {
#pragma unroll
    for (int c = 0; c < 8; ++c) acc = fmaf(bf2f(wb[c]), a8[c], acc);
  } else {
#pragma unroll
    for (int c = 0; c < 8; ++c) acc = fmaf(wf[c], a8[c], acc);
  }
  return acc;
}

// per-wave fused load + rmsnorm + ln scale, directly in dot layout:
// a[it*8+c] = x[it*512 + c*64 + lane] * ln[same] * rsqrt(mean(x^2)+eps).
// COH=1: coherent (sc) loads of cross-block data; COH=0: normal (immutable).
template <int COH>
__device__ __forceinline__ void load_row_rms(const float* __restrict__ x,
                                             const float* __restrict__ ln, float* a) {
  int lane = threadIdx.x & 63;
  float ssq = 0.f;
#pragma unroll
  for (int it = 0; it < 2; ++it)
#pragma unroll
    for (int c = 0; c < 8; ++c) {
      float v = COH ? ldc(x + it * 512 + c * 64 + lane) : x[it * 512 + c * 64 + lane];
      a[it * 8 + c] = v;
      ssq = fmaf(v, v, ssq);
    }
  float scale = rsqrtf(wred(ssq) * (1.f / D_MODEL) + EPS);
#pragma unroll
  for (int it = 0; it < 2; ++it)
#pragma unroll
    for (int c = 0; c < 8; ++c)
      a[it * 8 + c] *= ln[it * 512 + c * 64 + lane] * scale;
}

// transpose-convert f32 -> bf16 subtiles. w enumerates 16-BYTE dest words
// (8 bf16 each); wprl = log2(16B words per row): 7 for IN=1024, 9 for IN=4096.
// Written as TWO u64 sc-stores per 16B word (single-u64 pack was the R6/R7 bug).
__device__ __forceinline__ void conv_t(const float* __restrict__ src,
                                       unsigned long long* __restrict__ dst,
                                       size_t rows, int wprl) {
  size_t nw = rows << wprl;
  size_t stride = (size_t)NB * NT;
  for (size_t w = (size_t)blockIdx.x * NT + threadIdx.x; w < nw; w += stride) {
    size_t row = w >> wprl;
    int rem = (int)(w & (((size_t)1 << wprl) - 1));
    int it = rem >> 6, ln_ = rem & 63;
    const float* p = src + (row << (wprl + 3)) + it * 512 + ln_;
    unsigned long long lo = 0, hi = 0;
#pragma unroll
    for (int c = 0; c < 4; ++c)
      lo |= (unsigned long long)f2bf(p[c * 64]) << (16 * c);
#pragma unroll
    for (int c = 0; c < 4; ++c)
      hi |= (unsigned long long)f2bf(p[(c + 4) * 64]) << (16 * c);
    stc_u64(dst + 2 * w, lo);
    stc_u64(dst + 2 * w + 1, hi);
  }
}

struct KParams {
  const float *th, *c0, *ln1, *ln2, *lnf, *heads, *embeds;
  const float *fwq, *fwk, *fwv, *fwo, *fw1, *fw2, *fw3;
  unsigned short *bwq, *bwk, *bwv, *bwo, *bw1, *bw2, *bw3;
  float *out, *x, *qb, *ff, *pbv, *pbi, *esum, *kc, *vc;
  unsigned* bar;
};

__global__ void k_zero(unsigned* bar) {
  int i = blockIdx.x * 1024 + threadIdx.x;
  if (i < 4096) bar[i] = 0;
}

template <int BF>
__global__ __launch_bounds__(NT, 1) void mega(KParams P) {
  // LDS: attn 8K | qb 8K | small reduction scratch (block act staging removed:
  // per-wave fused load+rms makes phases LDS-free on the critical path)
  __shared__ float s_attn[2 * D_MODEL];
  __shared__ float s_qb[2 * D_MODEL];
  __shared__ float s_red[32];
  __shared__ float s_bval[16];
  __shared__ int s_bidx[16];
  __shared__ int s_code;

  unsigned gen = 0;
  const int tid = threadIdx.x, lane = tid & 63, wv_ = tid >> 6;
  const int bid = blockIdx.x;

  // per-thread task ids
  const int R_q = bid * 12 + wv_;                   // qkv row task (wv_<12)
  const int m_q = R_q >> 10;                        // 0=q,1=k,else v
  const int rr_q = R_q & 1023;
  const int h_q = rr_q >> 6, dd_q = rr_q & 63;
  const int wo_r = wv_ >> 1, wo_h = wv_ & 1;        // Wo: 4 rows x 2 halves (wv_<8)
  const int ff_j = bid * 16 + wv_;                  // ffup row
  const int w2_r = wv_ >> 2, w2_q = wv_ & 3;        // ffdown: 4 rows x 4 quarters
  const int lg_r = wv_ >> 1, lg_h = wv_ & 1;        // logits: 8 rows x 2 halves

  // prefetch fragments (unused variants DCE'd per BF)
  ushort8v pQ0{}, pQ1{}, pWo{}, p10{}, p11{}, p30{}, p31{}, pW20{}, pW21{};
  float pQf[16], pWof[8], p1f[16], p3f[16], pW2f[16], pHf[8];

  const size_t QKVO = (size_t)N_LAYERS * D_MODEL * D_MODEL;
  const size_t FFW = (size_t)N_LAYERS * D_FF * D_MODEL;

  // ---- phase 0: transpose-convert (bf16) + setup ----
  if constexpr (BF) {
    conv_t(P.fwq, (unsigned long long*)P.bwq, N_LAYERS * D_MODEL, 7);
    conv_t(P.fwk, (unsigned long long*)P.bwk, N_LAYERS * D_MODEL, 7);
    conv_t(P.fwv, (unsigned long long*)P.bwv, N_LAYERS * D_MODEL, 7);
    conv_t(P.fwo, (unsigned long long*)P.bwo, N_LAYERS * D_MODEL, 7);
    conv_t(P.fw1, (unsigned long long*)P.bw1, (size_t)N_LAYERS * D_FF, 7);
    conv_t(P.fw3, (unsigned long long*)P.bw3, (size_t)N_LAYERS * D_FF, 7);
    conv_t(P.fw2, (unsigned long long*)P.bw2, N_LAYERS * D_MODEL, 9);
  }
  if (bid == 0) {
    stc(&P.x[tid], P.th[tid]);
    stc(&P.x[D_MODEL + tid], P.c0[tid]);
    P.esum[tid] = P.c0[tid];  // block0-private
  }

  // hierarchical argmax: reduce 256 per-block (val,idx) pairs
  auto block_argmax = [&]() -> int {
    float v0 = -1e38f;
    int i0 = 0x7fffffff;
    if (tid < NB) {
      v0 = ldc(P.pbv + tid);
      i0 = (int)ldc(P.pbi + tid);
    }
#pragma unroll
    for (int o = 32; o > 0; o >>= 1) {
      float v2 = __shfl_xor(v0, o, 64);
      int i2 = __shfl_xor(i0, o, 64);
      if (v2 > v0 || (v2 == v0 && i2 < i0)) { v0 = v2; i0 = i2; }
    }
    if (lane == 0) { s_bval[wv_] = v0; s_bidx[wv_] = i0; }
    __syncthreads();
    if (tid == 0) {
      float b = s_bval[0];
      int bi = s_bidx[0];
#pragma unroll
      for (int w = 1; w < 4; ++w) {  // only waves 0..3 held candidates
        float v = s_bval[w];
        int i = s_bidx[w];
        if (v > b || (v == b && i < bi)) { b = v; bi = i; }
      }
      s_code = bi;
    }
    __syncthreads();
    return s_code;
  };

  auto pf_qkv = [&](int l) {
    const unsigned short* Wb = (m_q == 0) ? P.bwq : (m_q == 1) ? P.bwk : P.bwv;
    const float* Wf = (m_q == 0) ? P.fwq : (m_q == 1) ? P.fwk : P.fwv;
    size_t row = (size_t)l * D_MODEL + rr_q;
    ldsub<BF>(Wb, Wf, row, 2, 0, pQ0, pQf);
    ldsub<BF>(Wb, Wf, row, 2, 1, pQ1, pQf + 8);
  };
  auto pf_head = [&](const float* head) {
    const float* hp = head + (size_t)(bid * 8 + lg_r) * D_MODEL + lg_h * 512 + lane;
#pragma unroll
    for (int c = 0; c < 8; ++c) pHf[c] = hp[c * 64];
  };

  // ---- phases ----
  // hin: x (coherent) or embed row (immutable input, normal loads)
  auto qkv_phase = [&](const float* hin, bool hin_coh, int S, int start,
                       const float* ln, float* kcl, float* vcl) {
    if (wv_ < 12) {
      for (int s = 0; s < S; ++s) {
        float a[16];
        if (hin_coh) load_row_rms<1>(hin + s * D_MODEL, ln, a);
        else load_row_rms<0>(hin + s * D_MODEL, ln, a);
        float d = wred(dsub<BF>(pQ0, pQf, a) + dsub<BF>(pQ1, pQf + 8, a + 8));
        if (m_q >= 2) {
          if (lane == 0) stc(&vcl[(h_q * CACHE_LEN + start + s) * HEAD_DIM + dd_q], d);
        } else if (lane == 0) {
          s_red[s * 16 + wv_] = d;
        }
      }
    }
    __syncthreads();
    if (wv_ < 12 && m_q < 2 && !(rr_q & 1) && lane == 0) {
      int i = dd_q >> 1;
      float inv = powf(10000.f, -(float)(2 * i) / 64.f);
      for (int s = 0; s < S; ++s) {
        int pos = start + s;
        float d0 = s_red[s * 16 + wv_];
        float d1 = s_red[s * 16 + wv_ + 1];
        float ang = (float)pos * inv;
        float c = cosf(ang), sn = sinf(ang);
        float o0 = d0 * c - d1 * sn;
        float o1 = d0 * sn + d1 * c;
        if (m_q == 0) stc2(&P.qb[s * D_MODEL + rr_q], o0, o1);
        else stc2(&kcl[(h_q * CACHE_LEN + pos) * HEAD_DIM + dd_q], o0, o1);
      }
    }
  };

  // attention (normal cached K/V reads — rows written once per replay with
  // replay-identical values, never read before written) + Wo + residual.
  // Q staged wave-locally (producer == consumer wave, no block sync needed).
  auto aw_phase = [&](int S, int start, const float* kcl, const float* vcl) {
    int h = wv_;
    for (int s = 0; s < S; ++s)
      s_qb[s * D_MODEL + h * HEAD_DIM + lane] =
          ldc(&P.qb[s * D_MODEL + h * HEAD_DIM + lane]);
    for (int s = 0; s < S; ++s) {
      int pos = start + s;
      float scv = -1e30f;
      if (lane <= pos) {  // lane = cache position
        const float4* krow =
            (const float4*)(kcl + (size_t)(h * CACHE_LEN + lane) * HEAD_DIM);
        const float* q4 = s_qb + s * D_MODEL + h * HEAD_DIM;  // uniform -> broadcast
        float acc = 0.f;
#pragma unroll
        for (int d0 = 0; d0 < 16; ++d0) {
          float4 k = krow[d0];
          acc = fmaf(k.x, q4[d0 * 4], fmaf(k.y, q4[d0 * 4 + 1],
                fmaf(k.z, q4[d0 * 4 + 2], fmaf(k.w, q4[d0 * 4 + 3], acc))));
        }
        scv = acc * 0.125f;  // 1/sqrt(64)
      }
      float mx = wredmax(scv);
      float e = (lane <= pos) ? expf(scv - mx) : 0.f;
      float den = wred(e);
      float pr = e / den;
      float pv = 0.f;
#pragma unroll
      for (int t = 0; t < CACHE_LEN; ++t) {
        if (t <= pos)  // uniform branch: never touches unwritten rows
          pv = fmaf(__shfl(pr, t, 64),
                    vcl[(size_t)(h * CACHE_LEN + t) * HEAD_DIM + lane], pv);
      }
      s_attn[s * D_MODEL + h * HEAD_DIM + lane] = pv;
    }
    __syncthreads();
    if (wv_ < 8) {
      for (int s = 0; s < S; ++s) {
        float a8[8];
#pragma unroll
        for (int c = 0; c < 8; ++c)
          a8[c] = s_attn[s * D_MODEL + wo_h * 512 + c * 64 + lane];
        float part = wred(dsub<BF>(pWo, pWof, a8));
        if (lane == 0) s_red[s * 16 + wv_] = part;
      }
    }
    __syncthreads();
    if (tid < 4 * S) {
      int s = tid >> 2, rr = tid & 3;
      float* xp = &P.x[s * D_MODEL + bid * 4 + rr];
      stc(xp, ldc(xp) + s_red[s * 16 + rr * 2] + s_red[s * 16 + rr * 2 + 1]);
    }
  };

  auto ffup_phase = [&](int S, const float* ln2l) {
    for (int s = 0; s < S; ++s) {
      float a[16];
      load_row_rms<1>(P.x + s * D_MODEL, ln2l, a);
      float g = wred(dsub<BF>(p10, p1f, a) + dsub<BF>(p11, p1f + 8, a + 8));
      float u = wred(dsub<BF>(p30, p3f, a) + dsub<BF>(p31, p3f + 8, a + 8));
      if (lane == 0) stc(&P.ff[s * D_FF + ff_j], (g / (1.f + expf(-g))) * u);
    }
  };

  auto ffdown_phase = [&](int S) {
    for (int s = 0; s < S; ++s) {
      float a[16];
#pragma unroll
      for (int it = 0; it < 2; ++it)
#pragma unroll
        for (int c = 0; c < 8; ++c)
          a[it * 8 + c] =
              ldc(&P.ff[s * D_FF + w2_q * 1024 + it * 512 + c * 64 + lane]);
      float part = wred(dsub<BF>(pW20, pW2f, a) + dsub<BF>(pW21, pW2f + 8, a + 8));
      if (lane == 0) s_red[s * 16 + wv_] = part;
    }
    __syncthreads();
    if (tid < 4 * S) {
      int s = tid >> 2, rr2 = tid & 3;
      float v = s_red[s * 16 + rr2 * 4] + s_red[s * 16 + rr2 * 4 + 1] +
                s_red[s * 16 + rr2 * 4 + 2] + s_red[s * 16 + rr2 * 4 + 3];
      float* xp = &P.x[s * D_MODEL + bid * 4 + rr2];
      stc(xp, ldc(xp) + v);
    }
  };

  auto logits_phase = [&](int row, float* outg) {
    float a[16];
    load_row_rms<1>(P.x + row * D_MODEL, P.lnf, a);
    float d = 0.f;
#pragma unroll
    for (int c = 0; c < 8; ++c) d = fmaf(pHf[c], a[lg_h * 8 + c], d);
    d = wred(d);
    if (lane == 0) s_red[wv_] = d;
    __syncthreads();
    if (tid < 8) {
      float v = s_red[tid * 2] + s_red[tid * 2 + 1];
      outg[bid * 8 + tid] = v;
      s_red[16 + tid] = v;
    }
    __syncthreads();
    if (tid == 0) {  // per-block best (first-index tie-break within block)
      float b = s_red[16];
      int bi = 0;
#pragma unroll
      for (int j = 1; j < 8; ++j) {
        float v = s_red[16 + j];
        if (v > b) { b = v; bi = j; }
      }
      stc(&P.pbv[bid], b);
      stc(&P.pbi[bid], (float)(bid * 8 + bi));
    }
  };

  auto full_step = [&](int S, int start, bool am, const float* etab,
                       const float* next_head) {
    for (int l = 0; l < N_LAYERS; ++l) {
      float* kcl = P.kc + (size_t)l * N_HEADS * CACHE_LEN * HEAD_DIM;
      float* vcl = P.vc + (size_t)l * N_HEADS * CACHE_LEN * HEAD_DIM;
      const float* ln1l = P.ln1 + l * D_MODEL;
      if (am && l == 0) {
        int code = block_argmax();
        const float* hin = etab + (size_t)code * D_MODEL;
        if (bid == 0) {
          float e = hin[tid];
          stc(&P.x[tid], e);   // residual base row 0
          P.esum[tid] += e;
        }
        qkv_phase(hin, false, S, start, ln1l, kcl, vcl);
      } else {
        qkv_phase(P.x, true, S, start, ln1l, kcl, vcl);
      }
      ++gen;
      gsync_begin(P.bar, gen);
      if (wv_ < 8)
        ldsub<BF>(P.bwo, P.fwo, (size_t)l * D_MODEL + bid * 4 + wo_r, 2, wo_h, pWo, pWof);
      __builtin_amdgcn_sched_barrier(0);
      gsync_end(P.bar, gen);
      aw_phase(S, start, kcl, vcl);
      ++gen;
      gsync_begin(P.bar, gen);
      {
        size_t r1 = (size_t)l * D_FF + ff_j;
        ldsub<BF>(P.bw1, P.fw1, r1, 2, 0, p10, p1f);
        ldsub<BF>(P.bw1, P.fw1, r1, 2, 1, p11, p1f + 8);
        ldsub<BF>(P.bw3, P.fw3, r1, 2, 0, p30, p3f);
        ldsub<BF>(P.bw3, P.fw3, r1, 2, 1, p31, p3f + 8);
      }
      __builtin_amdgcn_sched_barrier(0);
      gsync_end(P.bar, gen);
      ffup_phase(S, P.ln2 + l * D_MODEL);
      ++gen;
      gsync_begin(P.bar, gen);
      {
        size_t r2 = (size_t)l * D_MODEL + bid * 4 + w2_r;
        ldsub<BF>(P.bw2, P.fw2, r2, 8, w2_q * 2, pW20, pW2f);
        ldsub<BF>(P.bw2, P.fw2, r2, 8, w2_q * 2 + 1, pW21, pW2f + 8);
      }
      __builtin_amdgcn_sched_barrier(0);
      gsync_end(P.bar, gen);
      ffdown_phase(S);
      ++gen;
      gsync_begin(P.bar, gen);
      if (l < N_LAYERS - 1) {
        if (wv_ < 12) pf_qkv(l + 1);
      } else {
        pf_head(next_head);
      }
      __builtin_amdgcn_sched_barrier(0);
      gsync_end(P.bar, gen);
    }
  };

  // ---- flow ----
  ++gen;
  gsync_begin(P.bar, gen);
  gsync_end(P.bar, gen);  // convert + setup complete
  if (wv_ < 12) pf_qkv(0);

  full_step(2, 0, false, nullptr, P.heads);  // prefill, positions {0,1}

  for (int g = 0; g < NUM_GROUPS; ++g) {
    logits_phase(g == 0 ? 1 : 0, P.out + (size_t)g * VOCAB);
    ++gen;
    gsync_begin(P.bar, gen);
    if (wv_ < 12) pf_qkv(0);  // next step's layer-0 qkv weights
    __builtin_amdgcn_sched_barrier(0);
    gsync_end(P.bar, gen);
    if (g < NUM_GROUPS - 1) {
      full_step(1, 2 + g, true, P.embeds + (size_t)g * VOCAB * D_MODEL,
                P.heads + (size_t)(g + 1) * VOCAB * D_MODEL);
    } else {
      // tail: last argmax -> embed_sum output (the step after it is dead)
      if (bid == 0) {
        int code = block_argmax();
        const float* emb =
            P.embeds + (size_t)g * VOCAB * D_MODEL + (size_t)code * D_MODEL;
        P.out[(size_t)NUM_GROUPS * VOCAB + tid] = P.esum[tid] + emb[tid];
      }
    }
  }
}

extern "C" void kernel_launch(void* const* d_in, const int* in_sizes, int n_in,
                              void* d_out, int out_size, void* d_ws, size_t ws_size,
                              hipStream_t stream) {
  KParams P;
  P.th = (const float*)d_in[0];
  P.c0 = (const float*)d_in[1];
  P.fwq = (const float*)d_in[2];
  P.fwk = (const float*)d_in[3];
  P.fwv = (const float*)d_in[4];
  P.fwo = (const float*)d_in[5];
  P.fw1 = (const float*)d_in[6];
  P.fw2 = (const float*)d_in[7];
  P.fw3 = (const float*)d_in[8];
  P.ln1 = (const float*)d_in[9];
  P.ln2 = (const float*)d_in[10];
  P.lnf = (const float*)d_in[11];
  P.heads = (const float*)d_in[12];
  P.embeds = (const float*)d_in[13];
  P.out = (float*)d_out;

  const size_t QKVO = (size_t)N_LAYERS * D_MODEL * D_MODEL;  // 4194304
  const size_t FFW = (size_t)N_LAYERS * D_FF * D_MODEL;      // 16777216
  const size_t W_ELEMS = 4 * QKVO + 3 * FFW;                 // 67108864
  // float scratch: x 2048 | qb 2048 | ff 8192 | pbv 256 | pbi 256 | esum 1024
  //              | kc 69632 | vc 69632
  const size_t SCRATCH = 2048 + 2048 + 8192 + 256 + 256 + 1024 + 69632 + 69632;
  const size_t NEED = W_ELEMS * 2 + SCRATCH * 4 + 4096 * 4;

  float* fs;
  int use_bf16 = (ws_size >= NEED);
  if (use_bf16) {
    unsigned short* wb = (unsigned short*)d_ws;
    P.bwq = wb;
    P.bwk = wb + QKVO;
    P.bwv = wb + 2 * QKVO;
    P.bwo = wb + 3 * QKVO;
    P.bw1 = wb + 4 * QKVO;
    P.bw3 = wb + 4 * QKVO + FFW;
    P.bw2 = wb + 4 * QKVO + 2 * FFW;
    fs = (float*)(wb + W_ELEMS);
  } else {
    P.bwq = P.bwk = P.bwv = P.bwo = P.bw1 = P.bw2 = P.bw3 = nullptr;
    fs = (float*)d_ws;
  }
  P.x = fs;
  P.qb = fs + 2048;
  P.ff = fs + 4096;
  P.pbv = fs + 12288;
  P.pbi = fs + 12544;
  P.esum = fs + 12800;
  P.kc = fs + 13824;
  P.vc = fs + 83456;
  P.bar = (unsigned*)(fs + SCRATCH);

  k_zero<<<4, 1024, 0, stream>>>(P.bar);
  void* args[] = {&P};
  if (use_bf16) {
    hipLaunchCooperativeKernel(reinterpret_cast<void*>(&mega<1>), dim3(NB), dim3(NT),
                               args, 0, stream);
  } else {
    hipLaunchCooperativeKernel(reinterpret_cast<void*>(&mega<0>), dim3(NB), dim3(NT),
                               args, 0, stream);
  }
}

// Round 11
// 1599.686 us; speedup vs baseline: 1.3038x; 1.3038x over previous
//
#include <hip/hip_runtime.h>
#include <math.h>

#define D_MODEL 1024
#define N_HEADS 16
#define HEAD_DIM 64
#define D_FF 4096
#define N_LAYERS 4
#define VOCAB 2048
#define NUM_GROUPS 15
#define CACHE_LEN 17
#define EPS 1e-6f
#define NB 256   // blocks (1 per CU)
#define NT 1024  // threads per block (16 waves)

typedef unsigned short ushort8v __attribute__((ext_vector_type(8)));

// ---------- coherent (device-scope) accessors ----------
__device__ __forceinline__ float ldc(const float* p) {
  return __hip_atomic_load((float*)p, __ATOMIC_RELAXED, __HIP_MEMORY_SCOPE_AGENT);
}
__device__ __forceinline__ void stc(float* p, float v) {
  __hip_atomic_store(p, v, __ATOMIC_RELAXED, __HIP_MEMORY_SCOPE_AGENT);
}
__device__ __forceinline__ void stc2(float* p, float a, float b) {
  union { unsigned long long u; float2 f; } c;
  c.f = make_float2(a, b);
  __hip_atomic_store((unsigned long long*)p, c.u, __ATOMIC_RELAXED,
                     __HIP_MEMORY_SCOPE_AGENT);
}
__device__ __forceinline__ void stc_u64(unsigned long long* p, unsigned long long v) {
  __hip_atomic_store(p, v, __ATOMIC_RELAXED, __HIP_MEMORY_SCOPE_AGENT);
}
__device__ __forceinline__ unsigned ldu(const unsigned* p) {
  return __hip_atomic_load((unsigned*)p, __ATOMIC_RELAXED, __HIP_MEMORY_SCOPE_AGENT);
}

__device__ __forceinline__ float bf2f(unsigned short u) {
  union { unsigned int i; float f; } c;
  c.i = ((unsigned int)u) << 16;
  return c.f;
}
__device__ __forceinline__ unsigned short f2bf(float f) {
  union { float f; unsigned int i; } c;
  c.f = f;
  unsigned int r = (c.i + 0x7fffu + ((c.i >> 16) & 1u)) >> 16;
  return (unsigned short)r;
}

__device__ __forceinline__ float wred(float v) {
#pragma unroll
  for (int o = 32; o > 0; o >>= 1) v += __shfl_xor(v, o, 64);
  return v;
}
__device__ __forceinline__ float wredmax(float v) {
#pragma unroll
  for (int o = 32; o > 0; o >>= 1) v = fmaxf(v, __shfl_xor(v, o, 64));
  return v;
}

// ---------- split flag-array grid barrier ----------
// flags[b*16] (64B apart), zeroed per call. begin = arrive; end = poll.
// Poll: thread t (t<NB) spins on block t's flag only; __syncthreads joins.
// Weight prefetch loads are issued BETWEEN begin and end to hide latency.
__device__ __forceinline__ void gsync_begin(unsigned* flags, unsigned gen) {
  __syncthreads();
  if (threadIdx.x == 0)
    __hip_atomic_store(flags + (size_t)blockIdx.x * 16u, gen, __ATOMIC_RELAXED,
                       __HIP_MEMORY_SCOPE_AGENT);
}
__device__ __forceinline__ void gsync_end(unsigned* flags, unsigned gen) {
  if (threadIdx.x < NB) {
    const unsigned* f = flags + (size_t)threadIdx.x * 16u;
    while (ldu(f) < gen) {          // first check without sleeping
      __builtin_amdgcn_s_sleep(1);
    }
  }
  __syncthreads();
}

// ---------- transposed-subtile weight access ----------
// bf16 storage: 16B word [(row*nsub + it)*64 + lane] holds elements
// {row*IN + it*512 + c*64 + lane}, c=0..7 (IN = nsub*512).
// f32 fallback: linear rows, scalar gather at the same element positions.
template <int BF>
__device__ __forceinline__ void ldsub(const unsigned short* Wb, const float* Wf,
                                      size_t row, int nsub, int it, ushort8v& ob,
                                      float* of) {
  int lane = threadIdx.x & 63;
  if constexpr (BF) {
    ob = ((const ushort8v*)Wb)[(row * nsub + it) * 64 + lane];
  } else {
    const float* p = Wf + row * (size_t)nsub * 512 + it * 512 + lane;
#pragma unroll
    for (int c = 0; c < 8; ++c) of[c] = p[c * 64];
  }
}

template <int BF>
__device__ __forceinline__ float dsub(const ushort8v& wb, const float* wf,
                                      const float* a8) {
  float acc = 0.f;
  if constexpr (BF) {
#pragma unroll
    for (int c = 0; c < 8; ++c) acc = fmaf(bf2f(wb[c]), a8[c], acc);
  } else {
#pragma unroll
    for (int c = 0; c < 8; ++c) acc = fmaf(wf[c], a8[c], acc);
  }
  return acc;
}

// conflict-free LDS act read: a8[c] = seg[c*64 + lane]
__device__ __forceinline__ void act8(const float* __restrict__ seg, float* a8) {
  int lane = threadIdx.x & 63;
#pragma unroll
  for (int c = 0; c < 8; ++c) a8[c] = seg[c * 64 + lane];
}

// transpose-convert f32 -> bf16 subtiles. w enumerates 16-BYTE dest words
// (8 bf16 each); wprl = log2(16B words per row): 7 for IN=1024, 9 for IN=4096.
// Written as TWO u64 sc-stores per 16B word (single-u64 pack was the R6/R7 bug).
__device__ __forceinline__ void conv_t(const float* __restrict__ src,
                                       unsigned long long* __restrict__ dst,
                                       size_t rows, int wprl) {
  size_t nw = rows << wprl;
  size_t stride = (size_t)NB * NT;
  for (size_t w = (size_t)blockIdx.x * NT + threadIdx.x; w < nw; w += stride) {
    size_t row = w >> wprl;
    int rem = (int)(w & (((size_t)1 << wprl) - 1));
    int it = rem >> 6, ln_ = rem & 63;
    const float* p = src + (row << (wprl + 3)) + it * 512 + ln_;
    unsigned long long lo = 0, hi = 0;
#pragma unroll
    for (int c = 0; c < 4; ++c)
      lo |= (unsigned long long)f2bf(p[c * 64]) << (16 * c);
#pragma unroll
    for (int c = 0; c < 4; ++c)
      hi |= (unsigned long long)f2bf(p[(c + 4) * 64]) << (16 * c);
    stc_u64(dst + 2 * w, lo);
    stc_u64(dst + 2 * w + 1, hi);
  }
}

struct KParams {
  const float *th, *c0, *ln1, *ln2, *lnf, *heads, *embeds;
  const float *fwq, *fwk, *fwv, *fwo, *fw1, *fw2, *fw3;
  unsigned short *bwq, *bwk, *bwv, *bwo, *bw1, *bw2, *bw3;
  float *out, *x, *qb, *ff, *pbv, *pbi, *esum, *kc, *vc;
  unsigned* bar;
};

__global__ void k_zero(unsigned* bar) {
  int i = blockIdx.x * 1024 + threadIdx.x;
  if (i < 4096) bar[i] = 0;
}

template <int BF>
__global__ __launch_bounds__(NT, 1) void mega(KParams P) {
  // LDS: attn 8K | xn 8K | ff 32K (qb aliases ff) | small reduction scratch
  __shared__ float s_attn[2 * D_MODEL];
  __shared__ float s_xn[2 * D_MODEL];
  __shared__ float s_ff[2 * D_FF];
  __shared__ float s_red[32];
  __shared__ float s_bval[16];
  __shared__ int s_bidx[16];
  __shared__ int s_code;
  float* s_qb = s_ff;  // aliased: qb staging (aw phase) vs ff staging (ffdown)

  unsigned gen = 0;
  const int tid = threadIdx.x, lane = tid & 63, wv_ = tid >> 6;
  const int bid = blockIdx.x;

  // per-thread task ids
  const int R_q = bid * 12 + wv_;                   // qkv row task (wv_<12)
  const int m_q = R_q >> 10;                        // 0=q,1=k,else v
  const int rr_q = R_q & 1023;
  const int h_q = rr_q >> 6, dd_q = rr_q & 63;
  const int wo_r = wv_ >> 1, wo_h = wv_ & 1;        // Wo: 4 rows x 2 halves (wv_<8)
  const int ff_j = bid * 16 + wv_;                  // ffup row
  const int w2_r = wv_ >> 2, w2_q = wv_ & 3;        // ffdown: 4 rows x 4 quarters
  const int lg_r = wv_ >> 1, lg_h = wv_ & 1;        // logits: 8 rows x 2 halves

  // prefetch fragments (unused variants DCE'd per BF)
  ushort8v pQ0{}, pQ1{}, pWo{}, p10{}, p11{}, p30{}, p31{}, pW20{}, pW21{};
  float pQf[16], pWof[8], p1f[16], p3f[16], pW2f[16], pHf[8];

  const size_t QKVO = (size_t)N_LAYERS * D_MODEL * D_MODEL;
  const size_t FFW = (size_t)N_LAYERS * D_FF * D_MODEL;

  // ---- phase 0: transpose-convert (bf16) + setup ----
  if constexpr (BF) {
    conv_t(P.fwq, (unsigned long long*)P.bwq, N_LAYERS * D_MODEL, 7);
    conv_t(P.fwk, (unsigned long long*)P.bwk, N_LAYERS * D_MODEL, 7);
    conv_t(P.fwv, (unsigned long long*)P.bwv, N_LAYERS * D_MODEL, 7);
    conv_t(P.fwo, (unsigned long long*)P.bwo, N_LAYERS * D_MODEL, 7);
    conv_t(P.fw1, (unsigned long long*)P.bw1, (size_t)N_LAYERS * D_FF, 7);
    conv_t(P.fw3, (unsigned long long*)P.bw3, (size_t)N_LAYERS * D_FF, 7);
    conv_t(P.fw2, (unsigned long long*)P.bw2, N_LAYERS * D_MODEL, 9);
  }
  if (bid == 0) {
    stc(&P.x[tid], P.th[tid]);
    stc(&P.x[D_MODEL + tid], P.c0[tid]);
    P.esum[tid] = P.c0[tid];  // block0-private
  }

  // ---- helpers ----
  auto stage_xn = [&](int s, const float* src, bool coh, const float* ln) {
    float v = coh ? ldc(src + tid) : src[tid];
    float p = wred(v * v);
    if ((tid & 63) == 0) s_red[tid >> 6] = p;
    __syncthreads();
    float t = 0.f;
#pragma unroll
    for (int w = 0; w < 16; ++w) t += s_red[w];
    float sc = rsqrtf(t * (1.f / D_MODEL) + EPS);
    s_xn[s * D_MODEL + tid] = v * ln[tid] * sc;
    __syncthreads();
  };

  // hierarchical argmax: reduce 256 per-block (val,idx) pairs
  auto block_argmax = [&]() -> int {
    float v0 = -1e38f;
    int i0 = 0x7fffffff;
    if (tid < NB) {
      v0 = ldc(P.pbv + tid);
      i0 = (int)ldc(P.pbi + tid);
    }
#pragma unroll
    for (int o = 32; o > 0; o >>= 1) {
      float v2 = __shfl_xor(v0, o, 64);
      int i2 = __shfl_xor(i0, o, 64);
      if (v2 > v0 || (v2 == v0 && i2 < i0)) { v0 = v2; i0 = i2; }
    }
    if (lane == 0) { s_bval[wv_] = v0; s_bidx[wv_] = i0; }
    __syncthreads();
    if (tid == 0) {
      float b = s_bval[0];
      int bi = s_bidx[0];
#pragma unroll
      for (int w = 1; w < 4; ++w) {  // only waves 0..3 held candidates
        float v = s_bval[w];
        int i = s_bidx[w];
        if (v > b || (v == b && i < bi)) { b = v; bi = i; }
      }
      s_code = bi;
    }
    __syncthreads();
    return s_code;
  };

  auto pf_qkv = [&](int l) {
    const unsigned short* Wb = (m_q == 0) ? P.bwq : (m_q == 1) ? P.bwk : P.bwv;
    const float* Wf = (m_q == 0) ? P.fwq : (m_q == 1) ? P.fwk : P.fwv;
    size_t row = (size_t)l * D_MODEL + rr_q;
    ldsub<BF>(Wb, Wf, row, 2, 0, pQ0, pQf);
    ldsub<BF>(Wb, Wf, row, 2, 1, pQ1, pQf + 8);
  };
  auto pf_head = [&](const float* head) {
    const float* hp = head + (size_t)(bid * 8 + lg_r) * D_MODEL + lg_h * 512 + lane;
#pragma unroll
    for (int c = 0; c < 8; ++c) pHf[c] = hp[c * 64];
  };

  // ---- phases ----
  auto qkv_phase = [&](int S, int start, float* kcl, float* vcl) {
    for (int s = 0; s < S; ++s) {
      if (wv_ < 12) {
        float a0[8], a1[8];
        act8(s_xn + s * D_MODEL, a0);
        act8(s_xn + s * D_MODEL + 512, a1);
        float d = wred(dsub<BF>(pQ0, pQf, a0) + dsub<BF>(pQ1, pQf + 8, a1));
        if (m_q >= 2) {
          if (lane == 0) stc(&vcl[(h_q * CACHE_LEN + start + s) * HEAD_DIM + dd_q], d);
        } else if (lane == 0) {
          s_red[s * 16 + wv_] = d;
        }
      }
    }
    __syncthreads();
    if (wv_ < 12 && m_q < 2 && !(rr_q & 1) && lane == 0) {
      int i = dd_q >> 1;
      float inv = powf(10000.f, -(float)(2 * i) / 64.f);
      for (int s = 0; s < S; ++s) {
        int pos = start + s;
        float d0 = s_red[s * 16 + wv_];
        float d1 = s_red[s * 16 + wv_ + 1];
        float ang = (float)pos * inv;
        float c = cosf(ang), sn = sinf(ang);
        float o0 = d0 * c - d1 * sn;
        float o1 = d0 * sn + d1 * c;
        if (m_q == 0) stc2(&P.qb[s * D_MODEL + rr_q], o0, o1);
        else stc2(&kcl[(h_q * CACHE_LEN + pos) * HEAD_DIM + dd_q], o0, o1);
      }
    }
  };

  // attention (normal cached K/V reads — rows written once per replay with
  // replay-identical values, never read before written) + Wo + residual.
  // Q staged wave-locally (producer == consumer wave, no block sync).
  auto aw_phase = [&](int S, int start, const float* kcl, const float* vcl) {
    int h = wv_;
    for (int s = 0; s < S; ++s)
      s_qb[s * D_MODEL + h * HEAD_DIM + lane] =
          ldc(&P.qb[s * D_MODEL + h * HEAD_DIM + lane]);
    for (int s = 0; s < S; ++s) {
      int pos = start + s;
      float scv = -1e30f;
      if (lane <= pos) {  // lane = cache position
        const float4* krow =
            (const float4*)(kcl + (size_t)(h * CACHE_LEN + lane) * HEAD_DIM);
        const float* q4 = s_qb + s * D_MODEL + h * HEAD_DIM;  // uniform -> broadcast
        float acc = 0.f;
#pragma unroll
        for (int d0 = 0; d0 < 16; ++d0) {
          float4 k = krow[d0];
          acc = fmaf(k.x, q4[d0 * 4], fmaf(k.y, q4[d0 * 4 + 1],
                fmaf(k.z, q4[d0 * 4 + 2], fmaf(k.w, q4[d0 * 4 + 3], acc))));
        }
        scv = acc * 0.125f;  // 1/sqrt(64)
      }
      float mx = wredmax(scv);
      float e = (lane <= pos) ? expf(scv - mx) : 0.f;
      float den = wred(e);
      float pr = e / den;
      float pv = 0.f;
#pragma unroll
      for (int t = 0; t < CACHE_LEN; ++t) {
        if (t <= pos)  // uniform branch: never touches unwritten rows
          pv = fmaf(__shfl(pr, t, 64),
                    vcl[(size_t)(h * CACHE_LEN + t) * HEAD_DIM + lane], pv);
      }
      s_attn[s * D_MODEL + h * HEAD_DIM + lane] = pv;
    }
    __syncthreads();
    if (wv_ < 8) {
      for (int s = 0; s < S; ++s) {
        float a8[8];
        act8(s_attn + s * D_MODEL + wo_h * 512, a8);
        float part = wred(dsub<BF>(pWo, pWof, a8));
        if (lane == 0) s_red[s * 16 + wv_] = part;
      }
    }
    __syncthreads();
    if (tid < 4 * S) {
      int s = tid >> 2, rr = tid & 3;
      float* xp = &P.x[s * D_MODEL + bid * 4 + rr];
      stc(xp, ldc(xp) + s_red[s * 16 + rr * 2] + s_red[s * 16 + rr * 2 + 1]);
    }
  };

  auto ffup_phase = [&](int S) {
    for (int s = 0; s < S; ++s) {
      float a0[8], a1[8];
      act8(s_xn + s * D_MODEL, a0);
      act8(s_xn + s * D_MODEL + 512, a1);
      float g = wred(dsub<BF>(p10, p1f, a0) + dsub<BF>(p11, p1f + 8, a1));
      float u = wred(dsub<BF>(p30, p3f, a0) + dsub<BF>(p31, p3f + 8, a1));
      if (lane == 0) stc(&P.ff[s * D_FF + ff_j], (g / (1.f + expf(-g))) * u);
    }
  };

  auto ffdown_phase = [&](int S) {
    for (int s = 0; s < S; ++s) {
#pragma unroll
      for (int k = 0; k < 4; ++k)
        s_ff[s * D_FF + k * 1024 + tid] = ldc(&P.ff[s * D_FF + k * 1024 + tid]);
    }
    __syncthreads();
    for (int s = 0; s < S; ++s) {
      float a0[8], a1[8];
      act8(s_ff + s * D_FF + w2_q * 1024, a0);
      act8(s_ff + s * D_FF + w2_q * 1024 + 512, a1);
      float part = wred(dsub<BF>(pW20, pW2f, a0) + dsub<BF>(pW21, pW2f + 8, a1));
      if (lane == 0) s_red[s * 16 + wv_] = part;
    }
    __syncthreads();
    if (tid < 4 * S) {
      int s = tid >> 2, rr2 = tid & 3;
      float v = s_red[s * 16 + rr2 * 4] + s_red[s * 16 + rr2 * 4 + 1] +
                s_red[s * 16 + rr2 * 4 + 2] + s_red[s * 16 + rr2 * 4 + 3];
      float* xp = &P.x[s * D_MODEL + bid * 4 + rr2];
      stc(xp, ldc(xp) + v);
    }
  };

  auto logits_phase = [&](int row, float* outg) {
    stage_xn(0, P.x + row * D_MODEL, true, P.lnf);
    float a8[8];
    act8(s_xn + lg_h * 512, a8);
    float d = 0.f;
#pragma unroll
    for (int c = 0; c < 8; ++c) d = fmaf(pHf[c], a8[c], d);
    d = wred(d);
    if (lane == 0) s_red[wv_] = d;
    __syncthreads();
    if (tid < 8) {
      float v = s_red[tid * 2] + s_red[tid * 2 + 1];
      outg[bid * 8 + tid] = v;
      s_red[16 + tid] = v;
    }
    __syncthreads();
    if (tid == 0) {  // per-block best (first-index tie-break within block)
      float b = s_red[16];
      int bi = 0;
#pragma unroll
      for (int j = 1; j < 8; ++j) {
        float v = s_red[16 + j];
        if (v > b) { b = v; bi = j; }
      }
      stc(&P.pbv[bid], b);
      stc(&P.pbi[bid], (float)(bid * 8 + bi));
    }
  };

  auto full_step = [&](int S, int start, bool am, const float* etab,
                       const float* next_head) {
    for (int l = 0; l < N_LAYERS; ++l) {
      float* kcl = P.kc + (size_t)l * N_HEADS * CACHE_LEN * HEAD_DIM;
      float* vcl = P.vc + (size_t)l * N_HEADS * CACHE_LEN * HEAD_DIM;
      const float* ln1l = P.ln1 + l * D_MODEL;
      if (am && l == 0) {
        int code = block_argmax();
        const float* hin = etab + (size_t)code * D_MODEL;
        if (bid == 0) {
          float e = hin[tid];
          stc(&P.x[tid], e);   // residual base row 0
          P.esum[tid] += e;
        }
        stage_xn(0, hin, false, ln1l);
      } else {
        for (int s = 0; s < S; ++s) stage_xn(s, P.x + s * D_MODEL, true, ln1l);
      }
      qkv_phase(S, start, kcl, vcl);
      ++gen;
      gsync_begin(P.bar, gen);
      if (wv_ < 8)
        ldsub<BF>(P.bwo, P.fwo, (size_t)l * D_MODEL + bid * 4 + wo_r, 2, wo_h, pWo, pWof);
      __builtin_amdgcn_sched_barrier(0);
      gsync_end(P.bar, gen);
      aw_phase(S, start, kcl, vcl);
      ++gen;
      gsync_begin(P.bar, gen);
      {
        size_t r1 = (size_t)l * D_FF + ff_j;
        ldsub<BF>(P.bw1, P.fw1, r1, 2, 0, p10, p1f);
        ldsub<BF>(P.bw1, P.fw1, r1, 2, 1, p11, p1f + 8);
        ldsub<BF>(P.bw3, P.fw3, r1, 2, 0, p30, p3f);
        ldsub<BF>(P.bw3, P.fw3, r1, 2, 1, p31, p3f + 8);
      }
      __builtin_amdgcn_sched_barrier(0);
      gsync_end(P.bar, gen);
      {
        const float* ln2l = P.ln2 + l * D_MODEL;
        for (int s = 0; s < S; ++s) stage_xn(s, P.x + s * D_MODEL, true, ln2l);
      }
      ffup_phase(S);
      ++gen;
      gsync_begin(P.bar, gen);
      {
        size_t r2 = (size_t)l * D_MODEL + bid * 4 + w2_r;
        ldsub<BF>(P.bw2, P.fw2, r2, 8, w2_q * 2, pW20, pW2f);
        ldsub<BF>(P.bw2, P.fw2, r2, 8, w2_q * 2 + 1, pW21, pW2f + 8);
      }
      __builtin_amdgcn_sched_barrier(0);
      gsync_end(P.bar, gen);
      ffdown_phase(S);
      ++gen;
      gsync_begin(P.bar, gen);
      if (l < N_LAYERS - 1) {
        if (wv_ < 12) pf_qkv(l + 1);
      } else {
        pf_head(next_head);
      }
      __builtin_amdgcn_sched_barrier(0);
      gsync_end(P.bar, gen);
    }
  };

  // ---- flow ----
  ++gen;
  gsync_begin(P.bar, gen);
  gsync_end(P.bar, gen);  // convert + setup complete
  if (wv_ < 12) pf_qkv(0);

  full_step(2, 0, false, nullptr, P.heads);  // prefill, positions {0,1}

  for (int g = 0; g < NUM_GROUPS; ++g) {
    logits_phase(g == 0 ? 1 : 0, P.out + (size_t)g * VOCAB);
    ++gen;
    gsync_begin(P.bar, gen);
    if (wv_ < 12) pf_qkv(0);  // next step's layer-0 qkv weights
    __builtin_amdgcn_sched_barrier(0);
    gsync_end(P.bar, gen);
    if (g < NUM_GROUPS - 1) {
      full_step(1, 2 + g, true, P.embeds + (size_t)g * VOCAB * D_MODEL,
                P.heads + (size_t)(g + 1) * VOCAB * D_MODEL);
    } else {
      // tail: last argmax -> embed_sum output (the step after it is dead)
      if (bid == 0) {
        int code = block_argmax();
        const float* emb =
            P.embeds + (size_t)g * VOCAB * D_MODEL + (size_t)code * D_MODEL;
        P.out[(size_t)NUM_GROUPS * VOCAB + tid] = P.esum[tid] + emb[tid];
      }
    }
  }
}

extern "C" void kernel_launch(void* const* d_in, const int* in_sizes, int n_in,
                              void* d_out, int out_size, void* d_ws, size_t ws_size,
                              hipStream_t stream) {
  KParams P;
  P.th = (const float*)d_in[0];
  P.c0 = (const float*)d_in[1];
  P.fwq = (const float*)d_in[2];
  P.fwk = (const float*)d_in[3];
  P.fwv = (const float*)d_in[4];
  P.fwo = (const float*)d_in[5];
  P.fw1 = (const float*)d_in[6];
  P.fw2 = (const float*)d_in[7];
  P.fw3 = (const float*)d_in[8];
  P.ln1 = (const float*)d_in[9];
  P.ln2 = (const float*)d_in[10];
  P.lnf = (const float*)d_in[11];
  P.heads = (const float*)d_in[12];
  P.embeds = (const float*)d_in[13];
  P.out = (float*)d_out;

  const size_t QKVO = (size_t)N_LAYERS * D_MODEL * D_MODEL;  // 4194304
  const size_t FFW = (size_t)N_LAYERS * D_FF * D_MODEL;      // 16777216
  const size_t W_ELEMS = 4 * QKVO + 3 * FFW;                 // 67108864
  // float scratch: x 2048 | qb 2048 | ff 8192 | pbv 256 | pbi 256 | esum 1024
  //              | kc 69632 | vc 69632
  const size_t SCRATCH = 2048 + 2048 + 8192 + 256 + 256 + 1024 + 69632 + 69632;
  const size_t NEED = W_ELEMS * 2 + SCRATCH * 4 + 4096 * 4;

  float* fs;
  int use_bf16 = (ws_size >= NEED);
  if (use_bf16) {
    unsigned short* wb = (unsigned short*)d_ws;
    P.bwq = wb;
    P.bwk = wb + QKVO;
    P.bwv = wb + 2 * QKVO;
    P.bwo = wb + 3 * QKVO;
    P.bw1 = wb + 4 * QKVO;
    P.bw3 = wb + 4 * QKVO + FFW;
    P.bw2 = wb + 4 * QKVO + 2 * FFW;
    fs = (float*)(wb + W_ELEMS);
  } else {
    P.bwq = P.bwk = P.bwv = P.bwo = P.bw1 = P.bw2 = P.bw3 = nullptr;
    fs = (float*)d_ws;
  }
  P.x = fs;
  P.qb = fs + 2048;
  P.ff = fs + 4096;
  P.pbv = fs + 12288;
  P.pbi = fs + 12544;
  P.esum = fs + 12800;
  P.kc = fs + 13824;
  P.vc = fs + 83456;
  P.bar = (unsigned*)(fs + SCRATCH);

  k_zero<<<4, 1024, 0, stream>>>(P.bar);
  void* args[] = {&P};
  if (use_bf16) {
    hipLaunchCooperativeKernel(reinterpret_cast<void*>(&mega<1>), dim3(NB), dim3(NT),
                               args, 0, stream);
  } else {
    hipLaunchCooperativeKernel(reinterpret_cast<void*>(&mega<0>), dim3(NB), dim3(NT),
                               args, 0, stream);
  }
}